// Round 21
// baseline (144.732 us; speedup 1.0000x reference)
//
#include <hip/hip_runtime.h>
#include <hip/hip_bf16.h>
#include <cstdint>
#include <math.h>

#define D_MODEL 1024
#define NHEADS  16
#define DK      64
#define BATCH   2
#define SEQ     2048
#define M_TOTAL (BATCH*SEQ)   // 4096 rows
#define NSPLIT  2
#define NTS     (SEQ/64/NSPLIT)   // 16 tiles per split

using f32x4  = __attribute__((ext_vector_type(4)))  float;
using f32x16 = __attribute__((ext_vector_type(16))) float;
using s16x8  = __attribute__((ext_vector_type(8)))  short;

#define CSC (0.125f * 1.44269504088896341f)   // (1/sqrt(Dk)) * log2(e)

__device__ __forceinline__ unsigned short bf16r(float f) {
    __hip_bfloat16 h = __float2bfloat16(f);
    return *(unsigned short*)&h;
}
// HW packed convert: lo -> bits[15:0], hi -> bits[31:16], RNE
__device__ __forceinline__ uint32_t cvtpk(float lo, float hi) {
    uint32_t r;
    asm("v_cvt_pk_bf16_f32 %0, %1, %2" : "=v"(r) : "v"(lo), "v"(hi));
    return r;
}
__device__ __forceinline__ float b2f(unsigned short u) {
    uint32_t x = (uint32_t)u << 16;
    float f;
    __builtin_memcpy(&f, &x, 4);
    return f;
}

// ---------------------------------------------------------------------------
// Fused conversions, one launch:
//  blocks [0,2048):    fp32 x -> bf16 xb (8 elems/thread)
//  blocks [2048,6144): W transpose+convert, 32x32 tiles, z = (bid-2048)>>10
// ---------------------------------------------------------------------------
__global__ __launch_bounds__(256) void conv_all(const float* __restrict__ x,
                                                unsigned short* __restrict__ xb,
                                                const float* __restrict__ W0, const float* __restrict__ W1,
                                                const float* __restrict__ W2, const float* __restrict__ W3,
                                                unsigned short* __restrict__ T0, unsigned short* __restrict__ T1,
                                                unsigned short* __restrict__ T2, unsigned short* __restrict__ T3)
{
    __shared__ float tile[32][33];
    const int bid = blockIdx.x;
    const int t   = threadIdx.x;

    if (bid < 2048) {
        const size_t i = ((size_t)bid * 256 + t) * 8;
        const float4 a = *(const float4*)(x + i);
        const float4 b = *(const float4*)(x + i + 4);
        ushort4 r0, r1;
        r0.x = bf16r(a.x); r0.y = bf16r(a.y); r0.z = bf16r(a.z); r0.w = bf16r(a.w);
        r1.x = bf16r(b.x); r1.y = bf16r(b.y); r1.z = bf16r(b.z); r1.w = bf16r(b.w);
        *(ushort4*)(xb + i)     = r0;
        *(ushort4*)(xb + i + 4) = r1;
        return;
    }

    const int b2   = bid - 2048;
    const int z    = b2 >> 10;
    const int rest = b2 & 1023;
    const int kblk = rest & 31;
    const int nblk = rest >> 5;
    const float* W; unsigned short* T;
    switch (z) {
        case 0: W = W0; T = T0; break;
        case 1: W = W1; T = T1; break;
        case 2: W = W2; T = T2; break;
        default: W = W3; T = T3; break;
    }
    const int r  = t >> 3;
    const int c4 = (t & 7) * 4;
    const int k0 = kblk * 32;
    const int n0 = nblk * 32;

    const float4 v = *(const float4*)(W + (size_t)(k0 + r) * 1024 + n0 + c4);
    tile[r][c4 + 0] = v.x; tile[r][c4 + 1] = v.y; tile[r][c4 + 2] = v.z; tile[r][c4 + 3] = v.w;
    __syncthreads();
    ushort4 o;
    o.x = bf16r(tile[c4 + 0][r]);
    o.y = bf16r(tile[c4 + 1][r]);
    o.z = bf16r(tile[c4 + 2][r]);
    o.w = bf16r(tile[c4 + 3][r]);
    *(ushort4*)(T + (size_t)(n0 + r) * 1024 + k0 + c4) = o;
}

// ---------------------------------------------------------------------------
// bf16 MFMA GEMM (m97 structure), optional output scale. Takes m0/n0 so the
// caller controls the block->tile mapping (XCD swizzle).
// ---------------------------------------------------------------------------
template<int OUT_BF16>
__device__ __forceinline__ void gemm_mfma_body(const unsigned short* __restrict__ A,
                                               const unsigned short* __restrict__ Bt,
                                               const float* __restrict__ bias,
                                               void* __restrict__ C,
                                               float oscale, int m0, int n0)
{
    __shared__ unsigned short As[128 * 64];
    __shared__ unsigned short Bs[128 * 64];

    const int t    = threadIdx.x;
    const int w    = t >> 6;
    const int lane = t & 63;
    const int ln   = lane & 15;
    const int g    = lane >> 4;
    const int wr   = w >> 1, wc = w & 1;

    f32x4 acc[4][4];
#pragma unroll
    for (int mi = 0; mi < 4; ++mi)
#pragma unroll
        for (int ni = 0; ni < 4; ++ni)
#pragma unroll
            for (int j = 0; j < 4; ++j) acc[mi][ni][j] = 0.f;

    const int lrow = lane >> 3;
    const int lchk = (lane & 7) ^ lrow;
    const unsigned short* Ag = A  + (size_t)(m0 + w * 32 + lrow) * 1024 + lchk * 8;
    const unsigned short* Bg = Bt + (size_t)(n0 + w * 32 + lrow) * 1024 + lchk * 8;

    for (int kt = 0; kt < 16; ++kt) {
        const int k0 = kt * 64;
#pragma unroll
        for (int i = 0; i < 4; ++i) {
            __builtin_amdgcn_global_load_lds(Ag + (size_t)i * 8 * 1024 + k0,
                                             &As[(w * 32 + i * 8) * 64], 16, 0, 0);
            __builtin_amdgcn_global_load_lds(Bg + (size_t)i * 8 * 1024 + k0,
                                             &Bs[(w * 32 + i * 8) * 64], 16, 0, 0);
        }
        __syncthreads();

#pragma unroll
        for (int ks = 0; ks < 2; ++ks) {
            s16x8 af[4], bf[4];
#pragma unroll
            for (int mi = 0; mi < 4; ++mi) {
                const int row = wr * 64 + mi * 16 + ln;
                af[mi] = *(const s16x8*)((const char*)As + row * 128 +
                                         (((ks * 4 + g) ^ (ln & 7)) * 16));
            }
#pragma unroll
            for (int ni = 0; ni < 4; ++ni) {
                const int row = wc * 64 + ni * 16 + ln;
                bf[ni] = *(const s16x8*)((const char*)Bs + row * 128 +
                                         (((ks * 4 + g) ^ (ln & 7)) * 16));
            }
#pragma unroll
            for (int mi = 0; mi < 4; ++mi)
#pragma unroll
                for (int ni = 0; ni < 4; ++ni)
                    acc[mi][ni] = __builtin_amdgcn_mfma_f32_16x16x32_bf16(
                        af[mi], bf[ni], acc[mi][ni], 0, 0, 0);
        }
        __syncthreads();
    }

#pragma unroll
    for (int ni = 0; ni < 4; ++ni) {
        const int n = n0 + wc * 64 + ni * 16 + ln;
        const float bn = bias[n];
#pragma unroll
        for (int mi = 0; mi < 4; ++mi) {
            const int m = m0 + wr * 64 + mi * 16 + g * 4;
#pragma unroll
            for (int j = 0; j < 4; ++j) {
                const float v = (acc[mi][ni][j] + bn) * oscale;
                if constexpr (OUT_BF16)
                    ((unsigned short*)C)[(size_t)(m + j) * 1024 + n] = bf16r(v);
                else
                    ((float*)C)[(size_t)(m + j) * 1024 + n] = v;
            }
        }
    }
}

// ---------------------------------------------------------------------------
// Fused QKV GEMM, 1D XCD-swizzled grid: bid = m*24 + z*8 + n (r17 WIN: ~-6us).
// ---------------------------------------------------------------------------
__global__ __launch_bounds__(256) void qkv_mfma(const unsigned short* __restrict__ xb,
                                                const unsigned short* __restrict__ Wqt, const float* __restrict__ bq,
                                                const unsigned short* __restrict__ Wkt, const float* __restrict__ bk,
                                                const unsigned short* __restrict__ Wvt, const float* __restrict__ bv,
                                                unsigned short* __restrict__ Q,
                                                unsigned short* __restrict__ K,
                                                unsigned short* __restrict__ V)
{
    const int bid = blockIdx.x;
    const int m   = bid / 24;
    const int rr  = bid - m * 24;
    const int z   = rr >> 3;
    const int n   = rr & 7;
    const int m0  = m * 128;
    const int n0  = n * 128;

    if (z == 0)      gemm_mfma_body<1>(xb, Wqt, bq, Q, CSC, m0, n0);   // Q pre-scaled
    else if (z == 1) gemm_mfma_body<1>(xb, Wkt, bk, K, 1.0f, m0, n0);
    else             gemm_mfma_body<1>(xb, Wvt, bv, V, 1.0f, m0, n0);
}

// ---------------------------------------------------------------------------
// Output projection with FUSED split-combine (replaces attn_combine + Ab):
// A-operand is reg-staged from the two unnormalized split partials:
//   A[m][kt*64+d] = (b2f(Op0[prow][d]) + b2f(Op1[prow][d])) * rinv(prow)
// where prow = (b*16 + kt)*2048 + s (A's col block kt == head),
// rinv = 1/(l0+l1) from lbuf. LDS write uses the SAME chunk-XOR involution
// the fragment reads expect (row*128 + 16*(c ^ (row&7)) — proven K-stage
// pattern). B (Wot) stays global_load_lds. 2D grid: same-n blocks stride
// 8 == 0 (mod 8) -> W-panels already XCD-pinned.
// ---------------------------------------------------------------------------
__global__ __launch_bounds__(256) void oproj_fused(const unsigned short* __restrict__ Op0,
                                                   const unsigned short* __restrict__ Op1,
                                                   const float* __restrict__ lbuf,
                                                   const unsigned short* __restrict__ Wot,
                                                   const float* __restrict__ bo,
                                                   float* __restrict__ C)
{
    __shared__ unsigned short As[128 * 64];
    __shared__ unsigned short Bs[128 * 64];

    const int t    = threadIdx.x;
    const int w    = t >> 6;
    const int lane = t & 63;
    const int ln   = lane & 15;
    const int g    = lane >> 4;
    const int wr   = w >> 1, wc = w & 1;
    const int m0   = blockIdx.y * 128;
    const int n0   = blockIdx.x * 128;
    const size_t NROW = (size_t)BATCH * NHEADS * SEQ;

    f32x4 acc[4][4];
#pragma unroll
    for (int mi = 0; mi < 4; ++mi)
#pragma unroll
        for (int ni = 0; ni < 4; ++ni)
#pragma unroll
            for (int j = 0; j < 4; ++j) acc[mi][ni][j] = 0.f;

    const int lrow = lane >> 3;
    const int lchk = (lane & 7) ^ lrow;
    const int c8   = lane & 7;                    // A source chunk (8 d's)
    const unsigned short* Bg = Wot + (size_t)(n0 + w * 32 + lrow) * 1024 + lchk * 8;

    for (int kt = 0; kt < 16; ++kt) {
        const int k0 = kt * 64;
        // B staging (async, as before)
#pragma unroll
        for (int i = 0; i < 4; ++i)
            __builtin_amdgcn_global_load_lds(Bg + (size_t)i * 8 * 1024 + k0,
                                             &Bs[(w * 32 + i * 8) * 64], 16, 0, 0);
        // A staging: combine Op0+Op1, normalize, pack, swizzled ds_write
#pragma unroll
        for (int i = 0; i < 4; ++i) {
            const int row = w * 32 + i * 8 + lrow;      // 0..127 within tile
            const int m   = m0 + row;
            const int bb  = m >> 11;
            const int s   = m & 2047;
            const size_t prow = (size_t)(bb * 16 + kt) * 2048 + s;
            const float rinv = 1.0f / (lbuf[prow] + lbuf[NROW + prow]);
            const s16x8 u = *(const s16x8*)(Op0 + prow * DK + c8 * 8);
            const s16x8 v = *(const s16x8*)(Op1 + prow * DK + c8 * 8);
            union { uint32_t u32[4]; s16x8 v16; } F;
#pragma unroll
            for (int e = 0; e < 4; ++e) {
                const float lo = (b2f((unsigned short)u[2 * e])     + b2f((unsigned short)v[2 * e]))     * rinv;
                const float hi = (b2f((unsigned short)u[2 * e + 1]) + b2f((unsigned short)v[2 * e + 1])) * rinv;
                F.u32[e] = cvtpk(lo, hi);
            }
            *(s16x8*)((char*)As + row * 128 + 16 * (c8 ^ lrow)) = F.v16;
        }
        __syncthreads();   // drains vm (B) + lgkm (A ds_writes)

#pragma unroll
        for (int ks = 0; ks < 2; ++ks) {
            s16x8 af[4], bf[4];
#pragma unroll
            for (int mi = 0; mi < 4; ++mi) {
                const int row = wr * 64 + mi * 16 + ln;
                af[mi] = *(const s16x8*)((const char*)As + row * 128 +
                                         (((ks * 4 + g) ^ (ln & 7)) * 16));
            }
#pragma unroll
            for (int ni = 0; ni < 4; ++ni) {
                const int row = wc * 64 + ni * 16 + ln;
                bf[ni] = *(const s16x8*)((const char*)Bs + row * 128 +
                                         (((ks * 4 + g) ^ (ln & 7)) * 16));
            }
#pragma unroll
            for (int mi = 0; mi < 4; ++mi)
#pragma unroll
                for (int ni = 0; ni < 4; ++ni)
                    acc[mi][ni] = __builtin_amdgcn_mfma_f32_16x16x32_bf16(
                        af[mi], bf[ni], acc[mi][ni], 0, 0, 0);
        }
        __syncthreads();
    }

#pragma unroll
    for (int ni = 0; ni < 4; ++ni) {
        const int n = n0 + wc * 64 + ni * 16 + ln;
        const float bn = bo[n];
#pragma unroll
        for (int mi = 0; mi < 4; ++mi) {
            const int m = m0 + wr * 64 + mi * 16 + g * 4;
#pragma unroll
            for (int j = 0; j < 4; ++j)
                C[(size_t)(m + j) * 1024 + n] = acc[mi][ni][j] + bn;
        }
    }
}

// ---------------------------------------------------------------------------
// Flash attention, mfma_f32_32x32x16_bf16, KV-split=2. SESSION-BEST BODY
// (62.2us, r16/r18/r20): single K/V LDS buffer, reg-prefetch at loop top, 2
// barriers/tile, s_setprio(1) around MFMA clusters (r17 A/B: removing it
// costs +8us), 1D XCD-swizzled grid (r16: FETCH 70->19MB), m==0 no-max
// (r8+), pi-permuted V^T staging -> shuffle-free P pack (r9).
// r19: dual-tile ILP raises VGPR 64->84 (occupancy step, m69) -> regression.
// ---------------------------------------------------------------------------
__global__ __launch_bounds__(256, 4) void attn_mfma(const unsigned short* __restrict__ Qb,
                                                    const unsigned short* __restrict__ Kb,
                                                    const unsigned short* __restrict__ Vb,
                                                    unsigned short* __restrict__ O0,
                                                    unsigned short* __restrict__ O1,
                                                    float* __restrict__ lbuf)
{
    __shared__ unsigned short Klds [64 * 64];   // [key][d], chunk ^= key&7
    __shared__ unsigned short Vtlds[64 * 64];   // [d][pi-col], chunk ^= d&7

    const int t   = threadIdx.x;
    const int wid = t >> 6;
    const int l   = t & 63;
    const int q32 = l & 31;
    const int hi  = l >> 5;

    // swizzled 1D decode: bid = q*64 + (bh*2 + sp)
    const int bid = blockIdx.x;
    const int grp = bid & 63;
    const int qb  = bid >> 6;
    const int bh  = grp >> 1;
    const int sp  = grp & 1;
    const int b   = bh >> 4;
    const int h   = bh & 15;
    const int qbase = qb * 128 + wid * 32;
    const size_t qrow = (size_t)(b * SEQ + qbase + q32);
    const size_t kv0  = (size_t)(b * SEQ) + (size_t)sp * (SEQ / NSPLIT);

    // Q resident (B-frags): qf[ks] = Q[qrow][d = 16ks + 8hi .. +7]
    s16x8 qf[4];
    {
        const unsigned short* qp = Qb + qrow * D_MODEL + h * DK + 8 * hi;
#pragma unroll
        for (int ks = 0; ks < 4; ++ks) qf[ks] = *(const s16x8*)(qp + 16 * ks);
    }

    f32x16 ot0, ot1;   // O^T accum: d = crow(r,hi) + 32*{0,1}, col q = q32
#pragma unroll
    for (int i = 0; i < 16; ++i) { ot0[i] = 0.f; ot1[i] = 0.f; }
    float lsum = 0.f;

    // staging mappings (block-wide, 256 threads, 64 keys x 64 d)
    const int skey = t >> 3;
    const int sc8  = t & 7;
    const int vk2  = 2 * (t & 31);          // original (even) key
    const int pk2  = (vk2 & ~12) | ((vk2 & 4) << 1) | ((vk2 & 8) >> 1);  // pi(vk2)
    const int vd0  = 8 * (t >> 5);
    const unsigned short* Kg = Kb + (kv0 + skey) * D_MODEL + h * DK + 8 * sc8;
    const unsigned short* Vg = Vb + (kv0 + vk2) * D_MODEL + h * DK + vd0;
    char* const kw0 = (char*)Klds + skey * 128        + 16 * (sc8 ^ (skey & 7));
    char* const kw1 = (char*)Klds + (skey + 32) * 128 + 16 * (sc8 ^ (skey & 7));

    s16x8 kr0, kr1, vr0, vr1;

    auto load_regs = [&](int kt) {
        const size_t off = (size_t)kt * 64 * D_MODEL;
        kr0 = *(const s16x8*)(Kg + off);
        kr1 = *(const s16x8*)(Kg + off + (size_t)32 * D_MODEL);
        vr0 = *(const s16x8*)(Vg + off);
        vr1 = *(const s16x8*)(Vg + off + D_MODEL);
    };
    auto write_stage = [&]() {
        *(s16x8*)kw0 = kr0;
        *(s16x8*)kw1 = kr1;
#pragma unroll
        for (int i = 0; i < 8; ++i) {
            const int d = vd0 + i;
            const uint32_t val = (uint32_t)(unsigned short)vr0[i] |
                                 ((uint32_t)(unsigned short)vr1[i] << 16);
            *(uint32_t*)((char*)Vtlds + d * 128 +
                         16 * ((pk2 >> 3) ^ (d & 7)) + (pk2 & 7) * 2) = val;
        }
    };

    // prologue: stage tile 0
    load_regs(0);
    write_stage();
    __syncthreads();

    for (int kt = 0; kt < NTS; ++kt) {
        // issue next tile's global loads (consumed after barrier 1)
        if (kt < NTS - 1) load_regs(kt + 1);

        // ---- QK^T ----
        f32x16 s0, s1;
#pragma unroll
        for (int i = 0; i < 16; ++i) { s0[i] = 0.f; s1[i] = 0.f; }
        __builtin_amdgcn_s_setprio(1);
#pragma unroll
        for (int ks = 0; ks < 4; ++ks) {
            const int c = hi + 2 * ks;
            const s16x8 a0 = *(const s16x8*)((char*)Klds + q32 * 128 + 16 * (c ^ (q32 & 7)));
            const s16x8 a1 = *(const s16x8*)((char*)Klds + (q32 + 32) * 128 + 16 * (c ^ (q32 & 7)));
            s0 = __builtin_amdgcn_mfma_f32_32x32x16_bf16(a0, qf[ks], s0, 0, 0, 0);
            s1 = __builtin_amdgcn_mfma_f32_32x32x16_bf16(a1, qf[ks], s1, 0, 0, 0);
        }
        __builtin_amdgcn_s_setprio(0);

        // ---- softmax numerator, NO max subtraction (exp2 domain) ----
        float la = 0.f, lb = 0.f, lc = 0.f, ld = 0.f;
#pragma unroll
        for (int i = 0; i < 4; ++i) {
            s0[4 * i + 0] = exp2f(s0[4 * i + 0]); la += s0[4 * i + 0];
            s0[4 * i + 1] = exp2f(s0[4 * i + 1]); lb += s0[4 * i + 1];
            s0[4 * i + 2] = exp2f(s0[4 * i + 2]); lc += s0[4 * i + 2];
            s0[4 * i + 3] = exp2f(s0[4 * i + 3]); ld += s0[4 * i + 3];
            s1[4 * i + 0] = exp2f(s1[4 * i + 0]); la += s1[4 * i + 0];
            s1[4 * i + 1] = exp2f(s1[4 * i + 1]); lb += s1[4 * i + 1];
            s1[4 * i + 2] = exp2f(s1[4 * i + 2]); lc += s1[4 * i + 2];
            s1[4 * i + 3] = exp2f(s1[4 * i + 3]); ld += s1[4 * i + 3];
        }
        lsum += (la + lb) + (lc + ld);

        // ---- pack P -> PV B-frags: consecutive own registers (pi trick) ----
        s16x8 pf[4];
        {
            union { uint32_t u[4]; s16x8 v; } F;
#pragma unroll
            for (int e = 0; e < 4; ++e) F.u[e] = cvtpk(s0[2 * e], s0[2 * e + 1]);
            pf[0] = F.v;
#pragma unroll
            for (int e = 0; e < 4; ++e) F.u[e] = cvtpk(s0[8 + 2 * e], s0[9 + 2 * e]);
            pf[1] = F.v;
#pragma unroll
            for (int e = 0; e < 4; ++e) F.u[e] = cvtpk(s1[2 * e], s1[2 * e + 1]);
            pf[2] = F.v;
#pragma unroll
            for (int e = 0; e < 4; ++e) F.u[e] = cvtpk(s1[8 + 2 * e], s1[9 + 2 * e]);
            pf[3] = F.v;
        }

        // ---- PV: O^T += V^T(pi) . P^T ----
        __builtin_amdgcn_s_setprio(1);
#pragma unroll
        for (int ks = 0; ks < 4; ++ks) {
            const int c = hi + 2 * ks;
            const s16x8 av0 = *(const s16x8*)((char*)Vtlds + q32 * 128 + 16 * (c ^ (q32 & 7)));
            const s16x8 av1 = *(const s16x8*)((char*)Vtlds + (q32 + 32) * 128 + 16 * (c ^ (q32 & 7)));
            ot0 = __builtin_amdgcn_mfma_f32_32x32x16_bf16(av0, pf[ks], ot0, 0, 0, 0);
            ot1 = __builtin_amdgcn_mfma_f32_32x32x16_bf16(av1, pf[ks], ot1, 0, 0, 0);
        }
        __builtin_amdgcn_s_setprio(0);

        __syncthreads();                 // all waves done reading K/V LDS
        if (kt < NTS - 1) write_stage();
        __syncthreads();                 // next tile visible
    }

    // ---- store unnormalized bf16 partials + l ----
    const float ltot = lsum + __shfl_xor(lsum, 32);
    const size_t prow = (size_t)bh * SEQ + qbase + q32;   // (b,h,s) row index
    if (hi == 0)
        lbuf[(size_t)sp * (BATCH * NHEADS * SEQ) + prow] = ltot;

    unsigned short* op = ((sp == 0) ? O0 : O1) + prow * DK;
#pragma unroll
    for (int j = 0; j < 4; ++j) {
        uint2 st0, st1;
        st0.x = cvtpk(ot0[4 * j + 0], ot0[4 * j + 1]);
        st0.y = cvtpk(ot0[4 * j + 2], ot0[4 * j + 3]);
        st1.x = cvtpk(ot1[4 * j + 0], ot1[4 * j + 1]);
        st1.y = cvtpk(ot1[4 * j + 2], ot1[4 * j + 3]);
        *(uint2*)(op + 8 * j + 4 * hi)      = st0;
        *(uint2*)(op + 32 + 8 * j + 4 * hi) = st1;
    }
}

// ---------------------------------------------------------------------------
// ws layout (64 MB):
//   [0,8M)   xb (dead after qkv) -> lbuf overlay (512KB used)
//   [8,16M)  Wqt|Wkt|Wvt|Wot (Wot live until oproj)
//   [16,24M) Qb | [24,32M) Kb | [32,40M) Vb | [40,48M) (free; Ab removed)
//   [48,56M) Op0 | [56,64M) Op1
// All regions fully written before read each launch -> poison/replay safe.
// ---------------------------------------------------------------------------
extern "C" void kernel_launch(void* const* d_in, const int* in_sizes, int n_in,
                              void* d_out, int out_size, void* d_ws, size_t ws_size,
                              hipStream_t stream)
{
    const float* x  = (const float*)d_in[0];
    const float* Wq = (const float*)d_in[1];
    const float* bq = (const float*)d_in[2];
    const float* Wk = (const float*)d_in[3];
    const float* bk = (const float*)d_in[4];
    const float* Wv = (const float*)d_in[5];
    const float* bv = (const float*)d_in[6];
    const float* Wo = (const float*)d_in[7];
    const float* bo = (const float*)d_in[8];

    float* out = (float*)d_out;

    const size_t mat  = (size_t)M_TOTAL * D_MODEL;   // 4M elements
    const size_t wmat = (size_t)D_MODEL * D_MODEL;
    unsigned short* xb  = (unsigned short*)d_ws;
    unsigned short* Wqt = xb  + mat;
    unsigned short* Wkt = Wqt + wmat;
    unsigned short* Wvt = Wkt + wmat;
    unsigned short* Wot = Wvt + wmat;
    unsigned short* Qb  = Wot + wmat;
    unsigned short* Kb  = Qb  + mat;
    unsigned short* Vb  = Kb  + mat;
    unsigned short* Op0 = Vb  + mat + mat;      // [48,56M)
    unsigned short* Op1 = Op0 + mat;            // [56,64M)
    float*          lbuf = (float*)xb;          // overlay dead xb (512KB)

    conv_all<<<dim3(6144), 256, 0, stream>>>(x, xb, Wq, Wk, Wv, Wo, Wqt, Wkt, Wvt, Wot);

    // fused 1D XCD-swizzled grid: bid = m*24 + z*8 + n
    qkv_mfma<<<dim3(32 * 24), 256, 0, stream>>>(xb, Wqt, bq, Wkt, bk, Wvt, bv, Qb, Kb, Vb);

    // 1D swizzled grid: bid = q*64 + (bh*2+sp) -> q-blocks sharing K/V on one XCD
    attn_mfma<<<dim3((SEQ / 128) * BATCH * NHEADS * NSPLIT), 256, 0, stream>>>(
        Qb, Kb, Vb, Op0, Op1, lbuf);

    // output projection with fused split-combine (attn_combine kernel removed)
    oproj_fused<<<dim3(8, 32), 256, 0, stream>>>(Op0, Op1, lbuf, Wot, bo, out);
}

// Round 22
// 136.491 us; speedup vs baseline: 1.0604x; 1.0604x over previous
//
#include <hip/hip_runtime.h>
#include <hip/hip_bf16.h>
#include <cstdint>
#include <math.h>

#define D_MODEL 1024
#define NHEADS  16
#define DK      64
#define BATCH   2
#define SEQ     2048
#define M_TOTAL (BATCH*SEQ)   // 4096 rows
#define NSPLIT  2
#define NTS     (SEQ/64/NSPLIT)   // 16 tiles per split

using f32x4  = __attribute__((ext_vector_type(4)))  float;
using f32x16 = __attribute__((ext_vector_type(16))) float;
using s16x8  = __attribute__((ext_vector_type(8)))  short;

#define CSC (0.125f * 1.44269504088896341f)   // (1/sqrt(Dk)) * log2(e)

__device__ __forceinline__ unsigned short bf16r(float f) {
    __hip_bfloat16 h = __float2bfloat16(f);
    return *(unsigned short*)&h;
}
// HW packed convert: lo -> bits[15:0], hi -> bits[31:16], RNE
__device__ __forceinline__ uint32_t cvtpk(float lo, float hi) {
    uint32_t r;
    asm("v_cvt_pk_bf16_f32 %0, %1, %2" : "=v"(r) : "v"(lo), "v"(hi));
    return r;
}
__device__ __forceinline__ float b2f(unsigned short u) {
    uint32_t x = (uint32_t)u << 16;
    float f;
    __builtin_memcpy(&f, &x, 4);
    return f;
}

// ---------------------------------------------------------------------------
// Fused conversions, one launch:
//  blocks [0,2048):    fp32 x -> bf16 xb (8 elems/thread)
//  blocks [2048,6144): W transpose+convert, 32x32 tiles, z = (bid-2048)>>10
// ---------------------------------------------------------------------------
__global__ __launch_bounds__(256) void conv_all(const float* __restrict__ x,
                                                unsigned short* __restrict__ xb,
                                                const float* __restrict__ W0, const float* __restrict__ W1,
                                                const float* __restrict__ W2, const float* __restrict__ W3,
                                                unsigned short* __restrict__ T0, unsigned short* __restrict__ T1,
                                                unsigned short* __restrict__ T2, unsigned short* __restrict__ T3)
{
    __shared__ float tile[32][33];
    const int bid = blockIdx.x;
    const int t   = threadIdx.x;

    if (bid < 2048) {
        const size_t i = ((size_t)bid * 256 + t) * 8;
        const float4 a = *(const float4*)(x + i);
        const float4 b = *(const float4*)(x + i + 4);
        ushort4 r0, r1;
        r0.x = bf16r(a.x); r0.y = bf16r(a.y); r0.z = bf16r(a.z); r0.w = bf16r(a.w);
        r1.x = bf16r(b.x); r1.y = bf16r(b.y); r1.z = bf16r(b.z); r1.w = bf16r(b.w);
        *(ushort4*)(xb + i)     = r0;
        *(ushort4*)(xb + i + 4) = r1;
        return;
    }

    const int b2   = bid - 2048;
    const int z    = b2 >> 10;
    const int rest = b2 & 1023;
    const int kblk = rest & 31;
    const int nblk = rest >> 5;
    const float* W; unsigned short* T;
    switch (z) {
        case 0: W = W0; T = T0; break;
        case 1: W = W1; T = T1; break;
        case 2: W = W2; T = T2; break;
        default: W = W3; T = T3; break;
    }
    const int r  = t >> 3;
    const int c4 = (t & 7) * 4;
    const int k0 = kblk * 32;
    const int n0 = nblk * 32;

    const float4 v = *(const float4*)(W + (size_t)(k0 + r) * 1024 + n0 + c4);
    tile[r][c4 + 0] = v.x; tile[r][c4 + 1] = v.y; tile[r][c4 + 2] = v.z; tile[r][c4 + 3] = v.w;
    __syncthreads();
    ushort4 o;
    o.x = bf16r(tile[c4 + 0][r]);
    o.y = bf16r(tile[c4 + 1][r]);
    o.z = bf16r(tile[c4 + 2][r]);
    o.w = bf16r(tile[c4 + 3][r]);
    *(ushort4*)(T + (size_t)(n0 + r) * 1024 + k0 + c4) = o;
}

// ---------------------------------------------------------------------------
// bf16 MFMA GEMM (m97 structure), optional output scale. Takes m0/n0 so the
// caller controls the block->tile mapping (XCD swizzle).
// ---------------------------------------------------------------------------
template<int OUT_BF16>
__device__ __forceinline__ void gemm_mfma_body(const unsigned short* __restrict__ A,
                                               const unsigned short* __restrict__ Bt,
                                               const float* __restrict__ bias,
                                               void* __restrict__ C,
                                               float oscale, int m0, int n0)
{
    __shared__ unsigned short As[128 * 64];
    __shared__ unsigned short Bs[128 * 64];

    const int t    = threadIdx.x;
    const int w    = t >> 6;
    const int lane = t & 63;
    const int ln   = lane & 15;
    const int g    = lane >> 4;
    const int wr   = w >> 1, wc = w & 1;

    f32x4 acc[4][4];
#pragma unroll
    for (int mi = 0; mi < 4; ++mi)
#pragma unroll
        for (int ni = 0; ni < 4; ++ni)
#pragma unroll
            for (int j = 0; j < 4; ++j) acc[mi][ni][j] = 0.f;

    const int lrow = lane >> 3;
    const int lchk = (lane & 7) ^ lrow;
    const unsigned short* Ag = A  + (size_t)(m0 + w * 32 + lrow) * 1024 + lchk * 8;
    const unsigned short* Bg = Bt + (size_t)(n0 + w * 32 + lrow) * 1024 + lchk * 8;

    for (int kt = 0; kt < 16; ++kt) {
        const int k0 = kt * 64;
#pragma unroll
        for (int i = 0; i < 4; ++i) {
            __builtin_amdgcn_global_load_lds(Ag + (size_t)i * 8 * 1024 + k0,
                                             &As[(w * 32 + i * 8) * 64], 16, 0, 0);
            __builtin_amdgcn_global_load_lds(Bg + (size_t)i * 8 * 1024 + k0,
                                             &Bs[(w * 32 + i * 8) * 64], 16, 0, 0);
        }
        __syncthreads();

#pragma unroll
        for (int ks = 0; ks < 2; ++ks) {
            s16x8 af[4], bf[4];
#pragma unroll
            for (int mi = 0; mi < 4; ++mi) {
                const int row = wr * 64 + mi * 16 + ln;
                af[mi] = *(const s16x8*)((const char*)As + row * 128 +
                                         (((ks * 4 + g) ^ (ln & 7)) * 16));
            }
#pragma unroll
            for (int ni = 0; ni < 4; ++ni) {
                const int row = wc * 64 + ni * 16 + ln;
                bf[ni] = *(const s16x8*)((const char*)Bs + row * 128 +
                                         (((ks * 4 + g) ^ (ln & 7)) * 16));
            }
#pragma unroll
            for (int mi = 0; mi < 4; ++mi)
#pragma unroll
                for (int ni = 0; ni < 4; ++ni)
                    acc[mi][ni] = __builtin_amdgcn_mfma_f32_16x16x32_bf16(
                        af[mi], bf[ni], acc[mi][ni], 0, 0, 0);
        }
        __syncthreads();
    }

#pragma unroll
    for (int ni = 0; ni < 4; ++ni) {
        const int n = n0 + wc * 64 + ni * 16 + ln;
        const float bn = bias[n];
#pragma unroll
        for (int mi = 0; mi < 4; ++mi) {
            const int m = m0 + wr * 64 + mi * 16 + g * 4;
#pragma unroll
            for (int j = 0; j < 4; ++j) {
                const float v = (acc[mi][ni][j] + bn) * oscale;
                if constexpr (OUT_BF16)
                    ((unsigned short*)C)[(size_t)(m + j) * 1024 + n] = bf16r(v);
                else
                    ((float*)C)[(size_t)(m + j) * 1024 + n] = v;
            }
        }
    }
}

// ---------------------------------------------------------------------------
// Fused QKV GEMM, 1D XCD-swizzled grid: bid = m*24 + z*8 + n (r17 WIN: ~-6us).
// Same-(z,n) blocks stride 24 == 0 (mod 8) -> W-panel pinned per XCD; the 24
// blocks sharing A-panel m are temporally adjacent -> A hot across all 3 z.
// ---------------------------------------------------------------------------
__global__ __launch_bounds__(256) void qkv_mfma(const unsigned short* __restrict__ xb,
                                                const unsigned short* __restrict__ Wqt, const float* __restrict__ bq,
                                                const unsigned short* __restrict__ Wkt, const float* __restrict__ bk,
                                                const unsigned short* __restrict__ Wvt, const float* __restrict__ bv,
                                                unsigned short* __restrict__ Q,
                                                unsigned short* __restrict__ K,
                                                unsigned short* __restrict__ V)
{
    const int bid = blockIdx.x;
    const int m   = bid / 24;
    const int rr  = bid - m * 24;
    const int z   = rr >> 3;
    const int n   = rr & 7;
    const int m0  = m * 128;
    const int n0  = n * 128;

    if (z == 0)      gemm_mfma_body<1>(xb, Wqt, bq, Q, CSC, m0, n0);   // Q pre-scaled
    else if (z == 1) gemm_mfma_body<1>(xb, Wkt, bk, K, 1.0f, m0, n0);
    else             gemm_mfma_body<1>(xb, Wvt, bv, V, 1.0f, m0, n0);
}

__global__ __launch_bounds__(256) void oproj_mfma(const unsigned short* __restrict__ Ab,
                                                  const unsigned short* __restrict__ Wot,
                                                  const float* __restrict__ bo,
                                                  float* __restrict__ C)
{
    gemm_mfma_body<0>(Ab, Wot, bo, C, 1.0f, blockIdx.y * 128, blockIdx.x * 128);
}

// ---------------------------------------------------------------------------
// Flash attention, mfma_f32_32x32x16_bf16, KV-split=2. SESSION-BEST BODY
// (62.2us, r16/r18/r20): single K/V LDS buffer, reg-prefetch at loop top, 2
// barriers/tile, s_setprio(1) around MFMA clusters (r17 A/B: removing it
// costs +8us), 1D XCD-swizzled grid (r16: FETCH 70->19MB), m==0 no-max
// (r8+), pi-permuted V^T staging -> shuffle-free P pack (r9).
// r19: dual-tile ILP raises VGPR 64->84 (occupancy step, m69) -> regression.
// r21: fusing combine into oproj's K-loop costs ~1:1 in a lockstep kernel ->
// keep combine as a separate BW-floor kernel.
// ---------------------------------------------------------------------------
__global__ __launch_bounds__(256, 4) void attn_mfma(const unsigned short* __restrict__ Qb,
                                                    const unsigned short* __restrict__ Kb,
                                                    const unsigned short* __restrict__ Vb,
                                                    unsigned short* __restrict__ O0,
                                                    unsigned short* __restrict__ O1,
                                                    float* __restrict__ lbuf)
{
    __shared__ unsigned short Klds [64 * 64];   // [key][d], chunk ^= key&7
    __shared__ unsigned short Vtlds[64 * 64];   // [d][pi-col], chunk ^= d&7

    const int t   = threadIdx.x;
    const int wid = t >> 6;
    const int l   = t & 63;
    const int q32 = l & 31;
    const int hi  = l >> 5;

    // swizzled 1D decode: bid = q*64 + (bh*2 + sp)
    const int bid = blockIdx.x;
    const int grp = bid & 63;
    const int qb  = bid >> 6;
    const int bh  = grp >> 1;
    const int sp  = grp & 1;
    const int b   = bh >> 4;
    const int h   = bh & 15;
    const int qbase = qb * 128 + wid * 32;
    const size_t qrow = (size_t)(b * SEQ + qbase + q32);
    const size_t kv0  = (size_t)(b * SEQ) + (size_t)sp * (SEQ / NSPLIT);

    // Q resident (B-frags): qf[ks] = Q[qrow][d = 16ks + 8hi .. +7]
    s16x8 qf[4];
    {
        const unsigned short* qp = Qb + qrow * D_MODEL + h * DK + 8 * hi;
#pragma unroll
        for (int ks = 0; ks < 4; ++ks) qf[ks] = *(const s16x8*)(qp + 16 * ks);
    }

    f32x16 ot0, ot1;   // O^T accum: d = crow(r,hi) + 32*{0,1}, col q = q32
#pragma unroll
    for (int i = 0; i < 16; ++i) { ot0[i] = 0.f; ot1[i] = 0.f; }
    float lsum = 0.f;

    // staging mappings (block-wide, 256 threads, 64 keys x 64 d)
    const int skey = t >> 3;
    const int sc8  = t & 7;
    const int vk2  = 2 * (t & 31);          // original (even) key
    const int pk2  = (vk2 & ~12) | ((vk2 & 4) << 1) | ((vk2 & 8) >> 1);  // pi(vk2)
    const int vd0  = 8 * (t >> 5);
    const unsigned short* Kg = Kb + (kv0 + skey) * D_MODEL + h * DK + 8 * sc8;
    const unsigned short* Vg = Vb + (kv0 + vk2) * D_MODEL + h * DK + vd0;
    char* const kw0 = (char*)Klds + skey * 128        + 16 * (sc8 ^ (skey & 7));
    char* const kw1 = (char*)Klds + (skey + 32) * 128 + 16 * (sc8 ^ (skey & 7));

    s16x8 kr0, kr1, vr0, vr1;

    auto load_regs = [&](int kt) {
        const size_t off = (size_t)kt * 64 * D_MODEL;
        kr0 = *(const s16x8*)(Kg + off);
        kr1 = *(const s16x8*)(Kg + off + (size_t)32 * D_MODEL);
        vr0 = *(const s16x8*)(Vg + off);
        vr1 = *(const s16x8*)(Vg + off + D_MODEL);
    };
    auto write_stage = [&]() {
        *(s16x8*)kw0 = kr0;
        *(s16x8*)kw1 = kr1;
#pragma unroll
        for (int i = 0; i < 8; ++i) {
            const int d = vd0 + i;
            const uint32_t val = (uint32_t)(unsigned short)vr0[i] |
                                 ((uint32_t)(unsigned short)vr1[i] << 16);
            *(uint32_t*)((char*)Vtlds + d * 128 +
                         16 * ((pk2 >> 3) ^ (d & 7)) + (pk2 & 7) * 2) = val;
        }
    };

    // prologue: stage tile 0
    load_regs(0);
    write_stage();
    __syncthreads();

    for (int kt = 0; kt < NTS; ++kt) {
        // issue next tile's global loads (consumed after barrier 1)
        if (kt < NTS - 1) load_regs(kt + 1);

        // ---- QK^T ----
        f32x16 s0, s1;
#pragma unroll
        for (int i = 0; i < 16; ++i) { s0[i] = 0.f; s1[i] = 0.f; }
        __builtin_amdgcn_s_setprio(1);
#pragma unroll
        for (int ks = 0; ks < 4; ++ks) {
            const int c = hi + 2 * ks;
            const s16x8 a0 = *(const s16x8*)((char*)Klds + q32 * 128 + 16 * (c ^ (q32 & 7)));
            const s16x8 a1 = *(const s16x8*)((char*)Klds + (q32 + 32) * 128 + 16 * (c ^ (q32 & 7)));
            s0 = __builtin_amdgcn_mfma_f32_32x32x16_bf16(a0, qf[ks], s0, 0, 0, 0);
            s1 = __builtin_amdgcn_mfma_f32_32x32x16_bf16(a1, qf[ks], s1, 0, 0, 0);
        }
        __builtin_amdgcn_s_setprio(0);

        // ---- softmax numerator, NO max subtraction (exp2 domain) ----
        float la = 0.f, lb = 0.f, lc = 0.f, ld = 0.f;
#pragma unroll
        for (int i = 0; i < 4; ++i) {
            s0[4 * i + 0] = exp2f(s0[4 * i + 0]); la += s0[4 * i + 0];
            s0[4 * i + 1] = exp2f(s0[4 * i + 1]); lb += s0[4 * i + 1];
            s0[4 * i + 2] = exp2f(s0[4 * i + 2]); lc += s0[4 * i + 2];
            s0[4 * i + 3] = exp2f(s0[4 * i + 3]); ld += s0[4 * i + 3];
            s1[4 * i + 0] = exp2f(s1[4 * i + 0]); la += s1[4 * i + 0];
            s1[4 * i + 1] = exp2f(s1[4 * i + 1]); lb += s1[4 * i + 1];
            s1[4 * i + 2] = exp2f(s1[4 * i + 2]); lc += s1[4 * i + 2];
            s1[4 * i + 3] = exp2f(s1[4 * i + 3]); ld += s1[4 * i + 3];
        }
        lsum += (la + lb) + (lc + ld);

        // ---- pack P -> PV B-frags: consecutive own registers (pi trick) ----
        s16x8 pf[4];
        {
            union { uint32_t u[4]; s16x8 v; } F;
#pragma unroll
            for (int e = 0; e < 4; ++e) F.u[e] = cvtpk(s0[2 * e], s0[2 * e + 1]);
            pf[0] = F.v;
#pragma unroll
            for (int e = 0; e < 4; ++e) F.u[e] = cvtpk(s0[8 + 2 * e], s0[9 + 2 * e]);
            pf[1] = F.v;
#pragma unroll
            for (int e = 0; e < 4; ++e) F.u[e] = cvtpk(s1[2 * e], s1[2 * e + 1]);
            pf[2] = F.v;
#pragma unroll
            for (int e = 0; e < 4; ++e) F.u[e] = cvtpk(s1[8 + 2 * e], s1[9 + 2 * e]);
            pf[3] = F.v;
        }

        // ---- PV: O^T += V^T(pi) . P^T ----
        __builtin_amdgcn_s_setprio(1);
#pragma unroll
        for (int ks = 0; ks < 4; ++ks) {
            const int c = hi + 2 * ks;
            const s16x8 av0 = *(const s16x8*)((char*)Vtlds + q32 * 128 + 16 * (c ^ (q32 & 7)));
            const s16x8 av1 = *(const s16x8*)((char*)Vtlds + (q32 + 32) * 128 + 16 * (c ^ (q32 & 7)));
            ot0 = __builtin_amdgcn_mfma_f32_32x32x16_bf16(av0, pf[ks], ot0, 0, 0, 0);
            ot1 = __builtin_amdgcn_mfma_f32_32x32x16_bf16(av1, pf[ks], ot1, 0, 0, 0);
        }
        __builtin_amdgcn_s_setprio(0);

        __syncthreads();                 // all waves done reading K/V LDS
        if (kt < NTS - 1) write_stage();
        __syncthreads();                 // next tile visible
    }

    // ---- store unnormalized bf16 partials + l ----
    const float ltot = lsum + __shfl_xor(lsum, 32);
    const size_t prow = (size_t)bh * SEQ + qbase + q32;   // (b,h,s) row index
    if (hi == 0)
        lbuf[(size_t)sp * (BATCH * NHEADS * SEQ) + prow] = ltot;

    unsigned short* op = ((sp == 0) ? O0 : O1) + prow * DK;
#pragma unroll
    for (int j = 0; j < 4; ++j) {
        uint2 st0, st1;
        st0.x = cvtpk(ot0[4 * j + 0], ot0[4 * j + 1]);
        st0.y = cvtpk(ot0[4 * j + 2], ot0[4 * j + 3]);
        st1.x = cvtpk(ot1[4 * j + 0], ot1[4 * j + 1]);
        st1.y = cvtpk(ot1[4 * j + 2], ot1[4 * j + 3]);
        *(uint2*)(op + 8 * j + 4 * hi)      = st0;
        *(uint2*)(op + 32 + 8 * j + 4 * hi) = st1;
    }
}

// ---------------------------------------------------------------------------
// Merge 2 KV-splits (m == 0): O = (Op0+Op1) / (l0+l1).
// ---------------------------------------------------------------------------
__global__ __launch_bounds__(256) void attn_combine(const unsigned short* __restrict__ O0,
                                                    const unsigned short* __restrict__ O1,
                                                    const float* __restrict__ lbuf,
                                                    unsigned short* __restrict__ Ab)
{
    const int tid = blockIdx.x * 256 + threadIdx.x;
    const int row = tid >> 3;             // 0 .. 65535
    const int d0  = (tid & 7) * 8;
    const size_t NROW = (size_t)BATCH * NHEADS * SEQ;

    const float rinv = 1.0f / (lbuf[row] + lbuf[NROW + row]);

    const size_t src = (size_t)row * DK + d0;
    const ushort4 a0 = *(const ushort4*)(O0 + src);
    const ushort4 a1 = *(const ushort4*)(O0 + src + 4);
    const ushort4 b0 = *(const ushort4*)(O1 + src);
    const ushort4 b1 = *(const ushort4*)(O1 + src + 4);

    const int bh = row >> 11, s = row & 2047;
    const int b = bh >> 4, h = bh & 15;
    unsigned short* dst = Ab + ((size_t)(b * SEQ + s)) * D_MODEL + h * DK + d0;

    ushort4 o0, o1;
    o0.x = bf16r((b2f(a0.x) + b2f(b0.x)) * rinv);
    o0.y = bf16r((b2f(a0.y) + b2f(b0.y)) * rinv);
    o0.z = bf16r((b2f(a0.z) + b2f(b0.z)) * rinv);
    o0.w = bf16r((b2f(a0.w) + b2f(b0.w)) * rinv);
    o1.x = bf16r((b2f(a1.x) + b2f(b1.x)) * rinv);
    o1.y = bf16r((b2f(a1.y) + b2f(b1.y)) * rinv);
    o1.z = bf16r((b2f(a1.z) + b2f(b1.z)) * rinv);
    o1.w = bf16r((b2f(a1.w) + b2f(b1.w)) * rinv);
    *(ushort4*)(dst)     = o0;
    *(ushort4*)(dst + 4) = o1;
}

// ---------------------------------------------------------------------------
// ws layout (64 MB):
//   [0,8M)   xb (dead after qkv) -> lbuf overlay (512KB used)
//   [8,16M)  Wqt|Wkt|Wvt|Wot (Wot live until oproj)
//   [16,24M) Qb | [24,32M) Kb | [32,40M) Vb | [40,48M) Ab
//   [48,56M) Op0 | [56,64M) Op1
// All regions fully written before read each launch -> poison/replay safe.
// ---------------------------------------------------------------------------
extern "C" void kernel_launch(void* const* d_in, const int* in_sizes, int n_in,
                              void* d_out, int out_size, void* d_ws, size_t ws_size,
                              hipStream_t stream)
{
    const float* x  = (const float*)d_in[0];
    const float* Wq = (const float*)d_in[1];
    const float* bq = (const float*)d_in[2];
    const float* Wk = (const float*)d_in[3];
    const float* bk = (const float*)d_in[4];
    const float* Wv = (const float*)d_in[5];
    const float* bv = (const float*)d_in[6];
    const float* Wo = (const float*)d_in[7];
    const float* bo = (const float*)d_in[8];

    float* out = (float*)d_out;

    const size_t mat  = (size_t)M_TOTAL * D_MODEL;   // 4M elements
    const size_t wmat = (size_t)D_MODEL * D_MODEL;
    unsigned short* xb  = (unsigned short*)d_ws;
    unsigned short* Wqt = xb  + mat;
    unsigned short* Wkt = Wqt + wmat;
    unsigned short* Wvt = Wkt + wmat;
    unsigned short* Wot = Wvt + wmat;
    unsigned short* Qb  = Wot + wmat;
    unsigned short* Kb  = Qb  + mat;
    unsigned short* Vb  = Kb  + mat;
    unsigned short* Ab  = Vb  + mat;
    unsigned short* Op0 = Ab  + mat;            // [48,56M)
    unsigned short* Op1 = Op0 + mat;            // [56,64M)
    float*          lbuf = (float*)xb;          // overlay dead xb (512KB)

    conv_all<<<dim3(6144), 256, 0, stream>>>(x, xb, Wq, Wk, Wv, Wo, Wqt, Wkt, Wvt, Wot);

    // fused 1D XCD-swizzled grid: bid = m*24 + z*8 + n
    qkv_mfma<<<dim3(32 * 24), 256, 0, stream>>>(xb, Wqt, bq, Wkt, bk, Wvt, bv, Qb, Kb, Vb);

    // 1D swizzled grid: bid = q*64 + (bh*2+sp) -> q-blocks sharing K/V on one XCD
    attn_mfma<<<dim3((SEQ / 128) * BATCH * NHEADS * NSPLIT), 256, 0, stream>>>(
        Qb, Kb, Vb, Op0, Op1, lbuf);

    attn_combine<<<dim3((BATCH * NHEADS * SEQ * 8) / 256), 256, 0, stream>>>(
        Op0, Op1, lbuf, Ab);

    oproj_mfma<<<dim3(8, 32), 256, 0, stream>>>(Ab, Wot, bo, out);
}